// Round 1
// 1412.117 us; speedup vs baseline: 1.0121x; 1.0121x over previous
//
#include <hip/hip_runtime.h>

// Problem: codes (1048576 x 256 f32), centroids (10 x 4 x 256 f32)
// -> out (1048576 x 10 f32): 1 - max_k dot(code, l2norm(centroid[c][k]))
//
// Memory-bound: 1.07 GB codes read @ ~6.3 TB/s => ~180 us floor.
//
// KEY CHANGE vs previous version: no d_ws usage. The previous two-kernel
// version staged normalized bf16 centroids in the 4 GiB workspace, which the
// harness re-poisons with a ~680 us 4.3 GB fill inside the timed region --
// that fill dominated the 1429 us measurement. Centroids are only 40 KiB, so
// each block now normalizes them into LDS (bf16, XOR-swizzled) in a short
// prologue and the harness has no workspace to poison.

typedef short short8 __attribute__((ext_vector_type(8)));
typedef float floatx4 __attribute__((ext_vector_type(4)));

#define NUM_CLASSES 10
#define DIM 256
#define NPAD 48   // 40 centroids padded to 3 N-tiles of 16

// fp32 -> bf16 round-to-nearest-even (bit trick; no NaN inputs here)
__device__ inline short f2bf(float f) {
  union { float f; unsigned u; } v; v.f = f;
  unsigned u = v.u;
  u += 0x7fffu + ((u >> 16) & 1u);
  return (short)(u >> 16);
}

// LDS layout: Bn[48][256] bf16 (24 KiB), n-major, with XOR swizzle on the
// short index: phys = row*256 + (col ^ ((row&7)<<3)).
// Read side (short8 at col = quad*8 + kt*32): 16 rows x same column would be a
// 16-way bank conflict unswizzled; with the swizzle each quad-group's 16B
// reads start at bank 4*((quad ^ (m&3)) | ...) -> rows 0..7 cover all 32
// banks, rows 8..15 repeat (2-way, free per m136).
__global__ __launch_bounds__(256) void dist_kernel(
    const float* __restrict__ codes, const float* __restrict__ cents,
    float* __restrict__ out) {
  __shared__ short Bn[NPAD * DIM];  // 24 KiB

  const int wid = threadIdx.x >> 6;   // wave in block: 0..3
  const int lane = threadIdx.x & 63;

  // ---- prologue: L2-normalize centroids (fp32) -> bf16 LDS, swizzled ----
  // wave w handles rows w*12 .. w*12+11; rows 40..47 are zero padding.
  #pragma unroll
  for (int i = 0; i < 12; ++i) {
    const int r = wid * 12 + i;
    short4 o = {0, 0, 0, 0};
    if (r < 40) {
      const float4 x = *(const float4*)(cents + r * DIM + lane * 4);
      float ss = x.x * x.x + x.y * x.y + x.z * x.z + x.w * x.w;
      #pragma unroll
      for (int off = 32; off > 0; off >>= 1) ss += __shfl_xor(ss, off);
      const float scale = 1.0f / fmaxf(sqrtf(ss), 1e-12f);
      o.x = f2bf(x.x * scale);
      o.y = f2bf(x.y * scale);
      o.z = f2bf(x.z * scale);
      o.w = f2bf(x.w * scale);
    }
    // write 4 shorts (8B); swizzle XOR touches short-index bits 3..5 only,
    // so 8B alignment and intra-chunk contiguity are preserved.
    *(short4*)(&Bn[r * DIM + ((lane * 4) ^ ((r & 7) << 3))]) = o;
  }
  __syncthreads();

  // ---- main: one wave per 16-row tile of codes ----
  const int wave = blockIdx.x * 4 + wid;
  const int m = lane & 15;
  const int quad = lane >> 4;
  const long base = (long)wave * 16;

  const float* arow = codes + (base + m) * DIM + quad * 8;

  // Swizzled LDS read addressing, decomposed:
  //   phys_short = m*256 + (quad ^ (m&3))*8 + (kt ^ ((m>>2)&1))*32
  // (valid because quad*8 occupies bits 3-4, kt*32 bits 5-7, XOR mask bits 3-5)
  const int qq = quad ^ (m & 3);
  const int kx = (m >> 2) & 1;
  const short* lb0 = Bn + (m + 0) * DIM + qq * 8;
  const short* lb1 = lb0 + 16 * DIM;
  const short* lb2 = lb0 + 32 * DIM;

  floatx4 acc0 = {0.f, 0.f, 0.f, 0.f};
  floatx4 acc1 = {0.f, 0.f, 0.f, 0.f};
  floatx4 acc2 = {0.f, 0.f, 0.f, 0.f};

  #pragma unroll
  for (int kt = 0; kt < 8; ++kt) {
    const float4 a0 = *(const float4*)(arow + kt * 32);
    const float4 a1 = *(const float4*)(arow + kt * 32 + 4);
    short8 af;
    af[0] = f2bf(a0.x); af[1] = f2bf(a0.y);
    af[2] = f2bf(a0.z); af[3] = f2bf(a0.w);
    af[4] = f2bf(a1.x); af[5] = f2bf(a1.y);
    af[6] = f2bf(a1.z); af[7] = f2bf(a1.w);
    const int ko = ((kt ^ kx) << 5);
    const short8 bf0 = *(const short8*)(lb0 + ko);
    const short8 bf1 = *(const short8*)(lb1 + ko);
    const short8 bf2 = *(const short8*)(lb2 + ko);
    acc0 = __builtin_amdgcn_mfma_f32_16x16x32_bf16(af, bf0, acc0, 0, 0, 0);
    acc1 = __builtin_amdgcn_mfma_f32_16x16x32_bf16(af, bf1, acc1, 0, 0, 0);
    acc2 = __builtin_amdgcn_mfma_f32_16x16x32_bf16(af, bf2, acc2, 0, 0, 0);
  }

  // C/D layout: col = lane&15 (centroid), row = quad*4 + reg.
  // class = centroid >> 2; max over 4 centroids = max over aligned 4-lane
  // group -> shfl_xor(1), shfl_xor(2).
  const int cls_in = m >> 2;
  #pragma unroll
  for (int j = 0; j < 3; ++j) {
    const floatx4 a = (j == 0) ? acc0 : (j == 1) ? acc1 : acc2;
    const int cls = j * 4 + cls_in;
    #pragma unroll
    for (int r = 0; r < 4; ++r) {
      float v = a[r];
      v = fmaxf(v, __shfl_xor(v, 1));
      v = fmaxf(v, __shfl_xor(v, 2));
      if ((lane & 3) == 0 && cls < NUM_CLASSES) {
        const long row = base + quad * 4 + r;
        out[row * NUM_CLASSES + cls] = 1.0f - v;
      }
    }
  }
}

extern "C" void kernel_launch(void* const* d_in, const int* in_sizes, int n_in,
                              void* d_out, int out_size, void* d_ws,
                              size_t ws_size, hipStream_t stream) {
  const float* codes = (const float*)d_in[0];      // (1048576, 256) f32
  const float* cents = (const float*)d_in[1];      // (10, 4, 256) f32
  float* out = (float*)d_out;                      // (1048576, 10) f32
  (void)d_ws; (void)ws_size;                       // workspace UNUSED (no poison fill)

  const int batch = in_sizes[0] / DIM;             // 1048576
  const int tiles = batch / 16;                    // 65536 waves
  const int blocks = tiles / 4;                    // 4 waves per block

  dist_kernel<<<dim3(blocks), dim3(256), 0, stream>>>(codes, cents, out);
}